// Round 17
// baseline (122.712 us; speedup 1.0000x reference)
//
#include <hip/hip_runtime.h>

typedef __bf16 bf16x8 __attribute__((ext_vector_type(8)));
typedef float f32x4 __attribute__((ext_vector_type(4)));
typedef float f32x16 __attribute__((ext_vector_type(16)));

#define S_LEN 4096

__device__ __forceinline__ unsigned short f2bf(float f) {
    unsigned int u = __float_as_uint(f);
    u += 0x7fffu + ((u >> 16) & 1u);
    return (unsigned short)(u >> 16);
}

__device__ __forceinline__ unsigned int pk_bf16(float lo, float hi) {
    unsigned int r;
    asm("v_cvt_pk_bf16_f32 %0, %1, %2" : "=v"(r) : "v"(lo), "v"(hi));
    return r;
}

__device__ __forceinline__ float bf2f(unsigned int hw) {
    return __uint_as_float(hw << 16);
}

// ---------- x (b,c,s) f32 -> xT (b,s,c) bf16 ; z==4 slice does weight conversion ----------
__global__ __launch_bounds__(256) void k_xt(const float* __restrict__ x, unsigned short* __restrict__ xT,
                                            const float* __restrict__ Wq, const float* __restrict__ Wkv,
                                            const float* __restrict__ Wp, unsigned short* __restrict__ wb,
                                            unsigned short* __restrict__ wpb) {
    __shared__ unsigned short tile[64 * 80];
    const int tid = threadIdx.x;
    if (blockIdx.z == 4) {
        const int bi = blockIdx.x + 64 * blockIdx.y;
        for (int i = bi * 256 + tid; i < 262144; i += 65536) {
            if (i < 65536)       wb[i]           = f2bf(Wq[i]);
            else if (i < 196608) wb[i]           = f2bf(Wkv[i - 65536]);
            else                 wpb[i - 196608] = f2bf(Wp[i - 196608]);
        }
        return;
    }
    const int b = blockIdx.z, c0 = blockIdx.y * 64, s0 = blockIdx.x * 64;
#pragma unroll
    for (int ii = 0; ii < 4; ++ii) {
        int flat = ii * 256 + tid;
        int cr = flat >> 4, s4 = flat & 15;
        const float4 v = *(const float4*)(x + ((size_t)(b * 256 + c0 + cr)) * S_LEN + s0 + s4 * 4);
        tile[(s4 * 4 + 0) * 80 + cr] = f2bf(v.x);
        tile[(s4 * 4 + 1) * 80 + cr] = f2bf(v.y);
        tile[(s4 * 4 + 2) * 80 + cr] = f2bf(v.z);
        tile[(s4 * 4 + 3) * 80 + cr] = f2bf(v.w);
    }
    __syncthreads();
#pragma unroll
    for (int ii = 0; ii < 2; ++ii) {
        int flat = ii * 256 + tid;
        int sr = flat >> 3, ch = flat & 7;
        uint4 u = *(const uint4*)&tile[sr * 80 + ch * 8];
        *(uint4*)(xT + ((size_t)(b * 4096 + s0 + sr)) * 256 + c0 + ch * 8) = u;
    }
}

// ---------- QKV GEMM (R14 version) -> q (pre-scaled) / k [b][h][s][32], v blocked ----------
__global__ __launch_bounds__(256) void k_qkv(const unsigned short* __restrict__ wb,
                                             const unsigned short* __restrict__ xT,
                                             const float* __restrict__ bq,
                                             const float* __restrict__ bkv,
                                             unsigned short* __restrict__ qws,
                                             unsigned short* __restrict__ kws,
                                             unsigned short* __restrict__ vws) {
    __shared__ unsigned short As[128 * 32];
    __shared__ unsigned short Bs[128 * 32];
    const int b = blockIdx.z;
    const int o0 = blockIdx.y * 128, s0 = blockIdx.x * 128;
    const int tid = threadIdx.x;
    const int w = tid >> 6, l = tid & 63, g = l >> 4, lc = l & 15;
    const int wr = w >> 1, wc = w & 1;
    const unsigned short* xb = xT + (size_t)b * 4096 * 256;
    const float SM_C = 0.25505654458f;  // log2(e)/sqrt(32) folded into q

    f32x4 acc[4][4];
#pragma unroll
    for (int m = 0; m < 4; ++m)
#pragma unroll
        for (int nf = 0; nf < 4; ++nf) acc[m][nf] = (f32x4)(0.f);

    const int lrow = tid >> 1, lhalf = tid & 1;
    const int lsw0 = (lrow * 64 + lhalf * 32) ^ ((lrow & 7) << 4);
    const int lsw1 = (lrow * 64 + lhalf * 32 + 16) ^ ((lrow & 7) << 4);

    for (int kk = 0; kk < 8; ++kk) {
        const int c0 = kk * 32;
        __syncthreads();
        {
            const uint4* srcA = (const uint4*)(wb + (size_t)(o0 + lrow) * 256 + c0 + lhalf * 16);
            uint4 a0 = srcA[0], a1 = srcA[1];
            const uint4* srcB = (const uint4*)(xb + (size_t)(s0 + lrow) * 256 + c0 + lhalf * 16);
            uint4 b0 = srcB[0], b1 = srcB[1];
            *(uint4*)((char*)As + lsw0) = a0;
            *(uint4*)((char*)As + lsw1) = a1;
            *(uint4*)((char*)Bs + lsw0) = b0;
            *(uint4*)((char*)Bs + lsw1) = b1;
        }
        __syncthreads();
        bf16x8 af[4], bfv[4];
#pragma unroll
        for (int m = 0; m < 4; ++m) {
            int row = wr * 64 + m * 16 + lc;
            af[m] = *(const bf16x8*)((char*)As + ((row * 64 + g * 16) ^ ((row & 7) << 4)));
        }
#pragma unroll
        for (int nf = 0; nf < 4; ++nf) {
            int row = wc * 64 + nf * 16 + lc;
            bfv[nf] = *(const bf16x8*)((char*)Bs + ((row * 64 + g * 16) ^ ((row & 7) << 4)));
        }
#pragma unroll
        for (int m = 0; m < 4; ++m)
#pragma unroll
            for (int nf = 0; nf < 4; ++nf)
                acc[m][nf] = __builtin_amdgcn_mfma_f32_16x16x32_bf16(af[m], bfv[nf], acc[m][nf], 0, 0, 0);
    }

#pragma unroll
    for (int m = 0; m < 4; ++m)
#pragma unroll
        for (int nf = 0; nf < 4; ++nf)
#pragma unroll
            for (int i = 0; i < 4; ++i) {
                int o = o0 + wr * 64 + m * 16 + g * 4 + i;
                int s = s0 + wc * 64 + nf * 16 + lc;
                if (o < 256) {
                    int h = o >> 5, d = o & 31;
                    qws[(((size_t)(b * 8 + h)) * 4096 + s) * 32 + d] = f2bf((acc[m][nf][i] + bq[o]) * SM_C);
                } else if (o < 512) {
                    int oo = o - 256, h = oo >> 5, d = oo & 31;
                    kws[(((size_t)(b * 8 + h)) * 4096 + s) * 32 + d] = f2bf(acc[m][nf][i] + bkv[o - 256]);
                } else {
                    int oo = o - 512, h = oo >> 5, d = oo & 31;
                    // blocked: [kb = s>>7][d][k' = s&127]
                    vws[(size_t)(b * 8 + h) * 131072 + (((s >> 7) * 32 + d) << 7) + (s & 127)] =
                        f2bf(acc[m][nf][i] + bkv[o - 256]);
                }
            }
}

// ---------- causal flash attention, k-split: every block <=17 rounds.
// ---------- mt<16: full job -> att. mt>=16: half0 -> pox0 partial; half1 -> att (unnormalized);
// ---------- k_combine normalizes in place. ----------
#define VC_STRIDE 544
#define BUF_STRIDE 8704   // 16 * 544

__device__ __forceinline__ void attn_sub(bf16x8 kf0, bf16x8 kf1,
                                         const char* __restrict__ vbuf, int c,
                                         bf16x8 qf0, bf16x8 qf1, const f32x16& zf, bf16x8 ones,
                                         int lane31, int hh, bool domask,
                                         f32x16& o, f32x16& sums) {
    bf16x8 vf0 = *(const bf16x8*)(vbuf + (c * 4 + hh) * VC_STRIDE + lane31 * 16);
    bf16x8 vf1 = *(const bf16x8*)(vbuf + (c * 4 + 2 + hh) * VC_STRIDE + lane31 * 16);

    f32x16 s = __builtin_amdgcn_mfma_f32_32x32x16_bf16(kf0, qf0, zf, 0, 0, 0);
    s = __builtin_amdgcn_mfma_f32_32x32x16_bf16(kf1, qf1, s, 0, 0, 0);

    if (domask) {
#pragma unroll
        for (int r = 0; r < 16; ++r) {
            int krel = (r & 3) + 8 * (r >> 2) + 4 * hh;
            if (krel > lane31) s[r] = -1e30f;
        }
    }

    float p[16];
#pragma unroll
    for (int r = 0; r < 16; ++r) p[r] = __builtin_amdgcn_exp2f(s[r]);

    unsigned int c00 = pk_bf16(p[0], p[1]),   c01 = pk_bf16(p[2], p[3]);
    unsigned int c10 = pk_bf16(p[4], p[5]),   c11 = pk_bf16(p[6], p[7]);
    unsigned int c20 = pk_bf16(p[8], p[9]),   c21 = pk_bf16(p[10], p[11]);
    unsigned int c30 = pk_bf16(p[12], p[13]), c31 = pk_bf16(p[14], p[15]);
    asm("v_permlane32_swap_b32 %0, %1" : "+v"(c00), "+v"(c10));
    asm("v_permlane32_swap_b32 %0, %1" : "+v"(c01), "+v"(c11));
    asm("v_permlane32_swap_b32 %0, %1" : "+v"(c20), "+v"(c30));
    asm("v_permlane32_swap_b32 %0, %1" : "+v"(c21), "+v"(c31));
    union U { uint4 u; bf16x8 v; };
    U pa0, pa1;
    pa0.u = make_uint4(c00, c01, c10, c11);
    pa1.u = make_uint4(c20, c21, c30, c31);

    sums = __builtin_amdgcn_mfma_f32_32x32x16_bf16(ones, pa0.v, sums, 0, 0, 0);
    sums = __builtin_amdgcn_mfma_f32_32x32x16_bf16(ones, pa1.v, sums, 0, 0, 0);
    o = __builtin_amdgcn_mfma_f32_32x32x16_bf16(vf0, pa0.v, o, 0, 0, 0);
    o = __builtin_amdgcn_mfma_f32_32x32x16_bf16(vf1, pa1.v, o, 0, 0, 0);
}

__global__ __launch_bounds__(256, 4) void k_attn(const unsigned short* __restrict__ qw,
                                                 const unsigned short* __restrict__ kw,
                                                 const unsigned short* __restrict__ vw,
                                                 unsigned short* __restrict__ att,
                                                 unsigned int* __restrict__ pox0,
                                                 float* __restrict__ psums) {
    __shared__ __align__(16) char smem[2 * BUF_STRIDE];

    const int tid = threadIdx.x;
    const int w = tid >> 6, l = tid & 63;
    const int lane31 = l & 31, hh = l >> 5;

    // XCD pinning (validated R4). 48 jobs per bh: 16 full (mt<16) + 32 halves (mt>=16).
    const int B = blockIdx.x;
    const int xcd = B & 7, idx = B >> 3;       // idx in [0,192)
    const int bh = xcd * 4 + (idx & 3);
    const int j = idx >> 2;                    // [0,48)

    int mt, r0, rlast, part0 = -1, half = 0;
    bool diag;
    if (j < 16) {
        mt = j; r0 = 0; rlast = mt; diag = true;
    } else {
        const int jj = j - 16;                 // [0,32)
        mt = 16 + (jj >> 1);
        half = jj & 1;
        const int h = (mt + 1) >> 1;
        if (half == 0) { r0 = 0; rlast = h - 1; diag = false; }
        else           { r0 = h; rlast = mt;    diag = true;  }
        part0 = bh * 16 + (mt - 16);           // [0,512)
    }

    const int q = mt * 128 + w * 32 + lane31;

    const unsigned short* qw_bh = qw + (size_t)bh * 4096 * 32;
    const unsigned short* kw_bh = kw + (size_t)bh * 4096 * 32;
    const unsigned short* vw_bh = vw + (size_t)bh * 131072;

    const bf16x8 qf0 = *(const bf16x8*)(qw_bh + (size_t)q * 32 + hh * 8);
    const bf16x8 qf1 = *(const bf16x8*)(qw_bh + (size_t)q * 32 + hh * 8 + 16);

    // V staging: blocked source, thread tid reads 32B at +tid*32B (wave = 2KB contiguous)
    const unsigned short* vsrc = vw_bh + tid * 16;
    const int vd0 = ((tid & 7) * 2) * VC_STRIDE + (tid >> 3) * 16;

    f32x16 o, sums, zf;
#pragma unroll
    for (int r = 0; r < 16; ++r) { o[r] = 0.f; sums[r] = 0.f; zf[r] = 0.f; }

    union OU { unsigned int u[4]; bf16x8 v; };
    OU onesU;
#pragma unroll
    for (int jj2 = 0; jj2 < 4; ++jj2) onesU.u[jj2] = 0x3F803F80u;  // bf16 1.0 x2
    const bf16x8 ones = onesU.v;

    // prologue: stage round r0 into buf0
    {
        const unsigned short* vp = vsrc + (size_t)r0 * 4096;
        uint4 va = *(const uint4*)(vp);
        uint4 vbb = *(const uint4*)(vp + 8);
        *(uint4*)(smem + vd0)             = va;
        *(uint4*)(smem + vd0 + VC_STRIDE) = vbb;
    }

    int cur = 0;
    // main rounds r0..rlast-1: fully below diagonal for all waves
    for (int r = r0; r < rlast; ++r) {
        const unsigned short* vp = vsrc + (size_t)(r + 1) * 4096;
        uint4 va = *(const uint4*)(vp);
        uint4 vbb = *(const uint4*)(vp + 8);

        __syncthreads();
        const char* vbuf = smem + cur * BUF_STRIDE;
        const unsigned short* kp = kw_bh + (size_t)(r * 128 + lane31) * 32 + hh * 8;
        bf16x8 kf[8];
#pragma unroll
        for (int c = 0; c < 4; ++c) {
            kf[2 * c]     = *(const bf16x8*)(kp + c * 1024);
            kf[2 * c + 1] = *(const bf16x8*)(kp + c * 1024 + 16);
        }
#pragma unroll
        for (int c = 0; c < 4; ++c)
            attn_sub(kf[2 * c], kf[2 * c + 1], vbuf, c, qf0, qf1, zf, ones, lane31, hh, false, o, sums);

        char* nb = smem + (cur ^ 1) * BUF_STRIDE;
        *(uint4*)(nb + vd0)             = va;
        *(uint4*)(nb + vd0 + VC_STRIDE) = vbb;
        cur ^= 1;
    }

    __syncthreads();
    // final round r = rlast: if diag -> wave w runs subs 0..w with mask at c==w; else full
    {
        const char* vbuf = smem + cur * BUF_STRIDE;
        const unsigned short* kp = kw_bh + (size_t)(rlast * 128 + lane31) * 32 + hh * 8;
        bf16x8 kf[8];
#pragma unroll
        for (int c = 0; c < 4; ++c) {
            kf[2 * c]     = *(const bf16x8*)(kp + c * 1024);
            kf[2 * c + 1] = *(const bf16x8*)(kp + c * 1024 + 16);
        }
        if (diag) {
#pragma unroll
            for (int c = 0; c < 4; ++c)
                if (c <= w)
                    attn_sub(kf[2 * c], kf[2 * c + 1], vbuf, c, qf0, qf1, zf, ones, lane31, hh, c == w, o, sums);
        } else {
#pragma unroll
            for (int c = 0; c < 4; ++c)
                attn_sub(kf[2 * c], kf[2 * c + 1], vbuf, c, qf0, qf1, zf, ones, lane31, hh, false, o, sums);
        }
    }

    if (part0 < 0) {
        const float inv = 1.0f / sums[0];
        unsigned int* dst = (unsigned int*)(att + (((size_t)(bh >> 3)) * 4096 + q) * 256 + (bh & 7) * 32);
#pragma unroll
        for (int jj2 = 0; jj2 < 8; ++jj2) {
            unsigned int v = pk_bf16(o[2 * jj2] * inv, o[2 * jj2 + 1] * inv);
            dst[(jj2 & 1) + 4 * (jj2 >> 1) + 2 * hh] = v;
        }
    } else if (half == 0) {
        unsigned int* po = pox0 + ((size_t)part0 * 256 + tid) * 8;
#pragma unroll
        for (int jj2 = 0; jj2 < 8; ++jj2)
            po[jj2] = pk_bf16(o[2 * jj2], o[2 * jj2 + 1]);
        psums[(size_t)(part0 * 2) * 256 + tid] = sums[0];
    } else {
        // unnormalized partial written directly into this q-row's att slot
        unsigned int* dst = (unsigned int*)(att + (((size_t)(bh >> 3)) * 4096 + q) * 256 + (bh & 7) * 32);
#pragma unroll
        for (int jj2 = 0; jj2 < 8; ++jj2)
            dst[(jj2 & 1) + 4 * (jj2 >> 1) + 2 * hh] = pk_bf16(o[2 * jj2], o[2 * jj2 + 1]);
        psums[(size_t)(part0 * 2 + 1) * 256 + tid] = sums[0];
    }
}

// ---------- combine partials for mt>=16 q-tiles (in place in att) ----------
__global__ __launch_bounds__(256) void k_combine(const unsigned int* __restrict__ pox0,
                                                 const float* __restrict__ psums,
                                                 unsigned short* __restrict__ att) {
    const int C = blockIdx.x;                  // [0,512)
    const int bh = C >> 4, mt = 16 + (C & 15);
    const int part0 = bh * 16 + (mt - 16);
    const int tid = threadIdx.x;
    const int w = tid >> 6, l = tid & 63;
    const int lane31 = l & 31, hh = l >> 5;

    const unsigned int* p0 = pox0 + ((size_t)part0 * 256 + tid) * 8;
    const float sum = psums[(size_t)(part0 * 2) * 256 + tid] + psums[(size_t)(part0 * 2 + 1) * 256 + tid];
    const float inv = 1.0f / sum;

    const int q = mt * 128 + w * 32 + lane31;
    unsigned int* dst = (unsigned int*)(att + (((size_t)(bh >> 3)) * 4096 + q) * 256 + (bh & 7) * 32);
#pragma unroll
    for (int jj = 0; jj < 8; ++jj) {
        const int di = (jj & 1) + 4 * (jj >> 1) + 2 * hh;
        unsigned int u0 = p0[jj], u1 = dst[di];
        float lo = bf2f(u0 & 0xffffu) + bf2f(u1 & 0xffffu);
        float hi = bf2f(u0 >> 16) + bf2f(u1 >> 16);
        dst[di] = pk_bf16(lo * inv, hi * inv);
    }
}

// ---------- output projection (R14 version) ----------
__global__ __launch_bounds__(256) void k_proj(const unsigned short* __restrict__ wpb,
                                              const unsigned short* __restrict__ att,
                                              const float* __restrict__ bp,
                                              float* __restrict__ out) {
    __shared__ unsigned short As[128 * 32];
    __shared__ unsigned short Bs[128 * 32];
    const int b = blockIdx.z;
    const int o0 = blockIdx.y * 128, s0 = blockIdx.x * 128;
    const int tid = threadIdx.x;
    const int w = tid >> 6, l = tid & 63, g = l >> 4, lc = l & 15;
    const int wr = w >> 1, wc = w & 1;
    const unsigned short* ab = att + (size_t)b * 4096 * 256;

    f32x4 acc[4][4];
#pragma unroll
    for (int m = 0; m < 4; ++m)
#pragma unroll
        for (int nf = 0; nf < 4; ++nf) acc[m][nf] = (f32x4)(0.f);

    const int lrow = tid >> 1, lhalf = tid & 1;
    const int lsw0 = (lrow * 64 + lhalf * 32) ^ ((lrow & 7) << 4);
    const int lsw1 = (lrow * 64 + lhalf * 32 + 16) ^ ((lrow & 7) << 4);

    for (int kk = 0; kk < 8; ++kk) {
        const int c0 = kk * 32;
        __syncthreads();
        {
            const uint4* srcA = (const uint4*)(wpb + (size_t)(o0 + lrow) * 256 + c0 + lhalf * 16);
            uint4 a0 = srcA[0], a1 = srcA[1];
            const uint4* srcB = (const uint4*)(ab + (size_t)(s0 + lrow) * 256 + c0 + lhalf * 16);
            uint4 b0 = srcB[0], b1 = srcB[1];
            *(uint4*)((char*)As + lsw0) = a0;
            *(uint4*)((char*)As + lsw1) = a1;
            *(uint4*)((char*)Bs + lsw0) = b0;
            *(uint4*)((char*)Bs + lsw1) = b1;
        }
        __syncthreads();
        bf16x8 af[4], bfv[4];
#pragma unroll
        for (int m = 0; m < 4; ++m) {
            int row = wr * 64 + m * 16 + lc;
            af[m] = *(const bf16x8*)((char*)As + ((row * 64 + g * 16) ^ ((row & 7) << 4)));
        }
#pragma unroll
        for (int nf = 0; nf < 4; ++nf) {
            int row = wc * 64 + nf * 16 + lc;
            bfv[nf] = *(const bf16x8*)((char*)Bs + ((row * 64 + g * 16) ^ ((row & 7) << 4)));
        }
#pragma unroll
        for (int m = 0; m < 4; ++m)
#pragma unroll
            for (int nf = 0; nf < 4; ++nf)
                acc[m][nf] = __builtin_amdgcn_mfma_f32_16x16x32_bf16(af[m], bfv[nf], acc[m][nf], 0, 0, 0);
    }

#pragma unroll
    for (int m = 0; m < 4; ++m)
#pragma unroll
        for (int nf = 0; nf < 4; ++nf)
#pragma unroll
            for (int i = 0; i < 4; ++i) {
                int o = o0 + wr * 64 + m * 16 + g * 4 + i;
                int s = s0 + wc * 64 + nf * 16 + lc;
                out[((size_t)(b * 256 + o)) * 4096 + s] = acc[m][nf][i] + bp[o];
            }
}

extern "C" void kernel_launch(void* const* d_in, const int* in_sizes, int n_in,
                              void* d_out, int out_size, void* d_ws, size_t ws_size,
                              hipStream_t stream) {
    const float* x   = (const float*)d_in[0];
    const float* Wq  = (const float*)d_in[1];
    const float* bq  = (const float*)d_in[2];
    const float* Wkv = (const float*)d_in[3];
    const float* bkv = (const float*)d_in[4];
    const float* Wp  = (const float*)d_in[5];
    const float* bp  = (const float*)d_in[6];
    float* out = (float*)d_out;
    char* ws = (char*)d_ws;

    unsigned short* wb  = (unsigned short*)(ws);              // 768*256*2
    unsigned short* wpb = (unsigned short*)(ws + 393216);     // 256*256*2
    unsigned short* xT  = (unsigned short*)(ws + 524288);     // 8 MB (reused by pox0/psums after k_qkv)
    unsigned short* qws = (unsigned short*)(ws + 8912896);
    unsigned short* kws = (unsigned short*)(ws + 17301504);
    unsigned short* vws = (unsigned short*)(ws + 25690112);
    unsigned short* att = (unsigned short*)(ws + 34078720);   // end 42467328 (max offset ever used)
    unsigned int*   pox0  = (unsigned int*)(ws + 524288);             // 512*256*8*4B = 4 MB
    float*          psums = (float*)(ws + 524288 + 4194304);          // 1024*256*4B = 1 MB (ends 5.77 MB)

    hipLaunchKernelGGL(k_xt, dim3(64, 4, 5), dim3(256), 0, stream, x, xT, Wq, Wkv, Wp, wb, wpb);
    hipLaunchKernelGGL(k_qkv, dim3(32, 6, 4), dim3(256), 0, stream, wb, xT, bq, bkv, qws, kws, vws);
    hipLaunchKernelGGL(k_attn, dim3(1536), dim3(256), 0, stream, qws, kws, vws, att, pox0, psums);
    hipLaunchKernelGGL(k_combine, dim3(512), dim3(256), 0, stream, pox0, psums, att);
    hipLaunchKernelGGL(k_proj, dim3(32, 2, 4), dim3(256), 0, stream, wpb, att, bp, out);
}

// Round 18
// 112.289 us; speedup vs baseline: 1.0928x; 1.0928x over previous
//
#include <hip/hip_runtime.h>

typedef __bf16 bf16x8 __attribute__((ext_vector_type(8)));
typedef float f32x4 __attribute__((ext_vector_type(4)));
typedef float f32x16 __attribute__((ext_vector_type(16)));

#define S_LEN 4096

__device__ __forceinline__ unsigned short f2bf(float f) {
    unsigned int u = __float_as_uint(f);
    u += 0x7fffu + ((u >> 16) & 1u);
    return (unsigned short)(u >> 16);
}

__device__ __forceinline__ unsigned int pk_bf16(float lo, float hi) {
    unsigned int r;
    asm("v_cvt_pk_bf16_f32 %0, %1, %2" : "=v"(r) : "v"(lo), "v"(hi));
    return r;
}

// ---------- x (b,c,s) f32 -> xT (b,s,c) bf16 ; z==4 slice does weight conversion ----------
__global__ __launch_bounds__(256) void k_xt(const float* __restrict__ x, unsigned short* __restrict__ xT,
                                            const float* __restrict__ Wq, const float* __restrict__ Wkv,
                                            const float* __restrict__ Wp, unsigned short* __restrict__ wb,
                                            unsigned short* __restrict__ wpb) {
    __shared__ unsigned short tile[64 * 80];
    const int tid = threadIdx.x;
    if (blockIdx.z == 4) {
        const int bi = blockIdx.x + 64 * blockIdx.y;
        for (int i = bi * 256 + tid; i < 262144; i += 65536) {
            if (i < 65536)       wb[i]           = f2bf(Wq[i]);
            else if (i < 196608) wb[i]           = f2bf(Wkv[i - 65536]);
            else                 wpb[i - 196608] = f2bf(Wp[i - 196608]);
        }
        return;
    }
    const int b = blockIdx.z, c0 = blockIdx.y * 64, s0 = blockIdx.x * 64;
#pragma unroll
    for (int ii = 0; ii < 4; ++ii) {
        int flat = ii * 256 + tid;
        int cr = flat >> 4, s4 = flat & 15;
        const float4 v = *(const float4*)(x + ((size_t)(b * 256 + c0 + cr)) * S_LEN + s0 + s4 * 4);
        tile[(s4 * 4 + 0) * 80 + cr] = f2bf(v.x);
        tile[(s4 * 4 + 1) * 80 + cr] = f2bf(v.y);
        tile[(s4 * 4 + 2) * 80 + cr] = f2bf(v.z);
        tile[(s4 * 4 + 3) * 80 + cr] = f2bf(v.w);
    }
    __syncthreads();
#pragma unroll
    for (int ii = 0; ii < 2; ++ii) {
        int flat = ii * 256 + tid;
        int sr = flat >> 3, ch = flat & 7;
        uint4 u = *(const uint4*)&tile[sr * 80 + ch * 8];
        *(uint4*)(xT + ((size_t)(b * 4096 + s0 + sr)) * 256 + c0 + ch * 8) = u;
    }
}

// ---------- QKV GEMM -> q (pre-scaled) / k [b][h][s][32], v blocked [b][h][s/128][d][s%128] ----------
__global__ __launch_bounds__(256) void k_qkv(const unsigned short* __restrict__ wb,
                                             const unsigned short* __restrict__ xT,
                                             const float* __restrict__ bq,
                                             const float* __restrict__ bkv,
                                             unsigned short* __restrict__ qws,
                                             unsigned short* __restrict__ kws,
                                             unsigned short* __restrict__ vws) {
    __shared__ unsigned short As[128 * 32];
    __shared__ unsigned short Bs[128 * 32];
    const int b = blockIdx.z;
    const int o0 = blockIdx.y * 128, s0 = blockIdx.x * 128;
    const int tid = threadIdx.x;
    const int w = tid >> 6, l = tid & 63, g = l >> 4, lc = l & 15;
    const int wr = w >> 1, wc = w & 1;
    const unsigned short* xb = xT + (size_t)b * 4096 * 256;
    const float SM_C = 0.25505654458f;  // log2(e)/sqrt(32) folded into q

    f32x4 acc[4][4];
#pragma unroll
    for (int m = 0; m < 4; ++m)
#pragma unroll
        for (int nf = 0; nf < 4; ++nf) acc[m][nf] = (f32x4)(0.f);

    const int lrow = tid >> 1, lhalf = tid & 1;
    const int lsw0 = (lrow * 64 + lhalf * 32) ^ ((lrow & 7) << 4);
    const int lsw1 = (lrow * 64 + lhalf * 32 + 16) ^ ((lrow & 7) << 4);

    for (int kk = 0; kk < 8; ++kk) {
        const int c0 = kk * 32;
        __syncthreads();
        {
            const uint4* srcA = (const uint4*)(wb + (size_t)(o0 + lrow) * 256 + c0 + lhalf * 16);
            uint4 a0 = srcA[0], a1 = srcA[1];
            const uint4* srcB = (const uint4*)(xb + (size_t)(s0 + lrow) * 256 + c0 + lhalf * 16);
            uint4 b0 = srcB[0], b1 = srcB[1];
            *(uint4*)((char*)As + lsw0) = a0;
            *(uint4*)((char*)As + lsw1) = a1;
            *(uint4*)((char*)Bs + lsw0) = b0;
            *(uint4*)((char*)Bs + lsw1) = b1;
        }
        __syncthreads();
        bf16x8 af[4], bfv[4];
#pragma unroll
        for (int m = 0; m < 4; ++m) {
            int row = wr * 64 + m * 16 + lc;
            af[m] = *(const bf16x8*)((char*)As + ((row * 64 + g * 16) ^ ((row & 7) << 4)));
        }
#pragma unroll
        for (int nf = 0; nf < 4; ++nf) {
            int row = wc * 64 + nf * 16 + lc;
            bfv[nf] = *(const bf16x8*)((char*)Bs + ((row * 64 + g * 16) ^ ((row & 7) << 4)));
        }
#pragma unroll
        for (int m = 0; m < 4; ++m)
#pragma unroll
            for (int nf = 0; nf < 4; ++nf)
                acc[m][nf] = __builtin_amdgcn_mfma_f32_16x16x32_bf16(af[m], bfv[nf], acc[m][nf], 0, 0, 0);
    }

#pragma unroll
    for (int m = 0; m < 4; ++m)
#pragma unroll
        for (int nf = 0; nf < 4; ++nf)
#pragma unroll
            for (int i = 0; i < 4; ++i) {
                int o = o0 + wr * 64 + m * 16 + g * 4 + i;
                int s = s0 + wc * 64 + nf * 16 + lc;
                if (o < 256) {
                    int h = o >> 5, d = o & 31;
                    qws[(((size_t)(b * 8 + h)) * 4096 + s) * 32 + d] = f2bf((acc[m][nf][i] + bq[o]) * SM_C);
                } else if (o < 512) {
                    int oo = o - 256, h = oo >> 5, d = oo & 31;
                    kws[(((size_t)(b * 8 + h)) * 4096 + s) * 32 + d] = f2bf(acc[m][nf][i] + bkv[o - 256]);
                } else {
                    int oo = o - 512, h = oo >> 5, d = oo & 31;
                    // blocked: [kb = s>>7][d][k' = s&127]
                    vws[(size_t)(b * 8 + h) * 131072 + (((s >> 7) * 32 + d) << 7) + (s & 127)] =
                        f2bf(acc[m][nf][i] + bkv[o - 256]);
                }
            }
}

// ---------- causal flash attention: 128-q block (4 waves), K hoisted per 128-key round,
// ---------- V blocked-global -> LDS, 256-key double rounds (1 barrier pair / 8 subs) ----------
#define VC_STRIDE 544
#define HALF_STRIDE 8704     // 16 * 544  (one 128-key round)
#define SLOT_STRIDE 17408    // two 128-key rounds per slot

__device__ __forceinline__ void attn_sub(bf16x8 kf0, bf16x8 kf1,
                                         const char* __restrict__ vbuf, int c,
                                         bf16x8 qf0, bf16x8 qf1, const f32x16& zf, bf16x8 ones,
                                         int lane31, int hh, bool domask,
                                         f32x16& o, f32x16& sums) {
    bf16x8 vf0 = *(const bf16x8*)(vbuf + (c * 4 + hh) * VC_STRIDE + lane31 * 16);
    bf16x8 vf1 = *(const bf16x8*)(vbuf + (c * 4 + 2 + hh) * VC_STRIDE + lane31 * 16);

    f32x16 s = __builtin_amdgcn_mfma_f32_32x32x16_bf16(kf0, qf0, zf, 0, 0, 0);
    s = __builtin_amdgcn_mfma_f32_32x32x16_bf16(kf1, qf1, s, 0, 0, 0);

    if (domask) {
#pragma unroll
        for (int r = 0; r < 16; ++r) {
            int krel = (r & 3) + 8 * (r >> 2) + 4 * hh;
            if (krel > lane31) s[r] = -1e30f;
        }
    }

    float p[16];
#pragma unroll
    for (int r = 0; r < 16; ++r) p[r] = __builtin_amdgcn_exp2f(s[r]);

    unsigned int c00 = pk_bf16(p[0], p[1]),   c01 = pk_bf16(p[2], p[3]);
    unsigned int c10 = pk_bf16(p[4], p[5]),   c11 = pk_bf16(p[6], p[7]);
    unsigned int c20 = pk_bf16(p[8], p[9]),   c21 = pk_bf16(p[10], p[11]);
    unsigned int c30 = pk_bf16(p[12], p[13]), c31 = pk_bf16(p[14], p[15]);
    asm("v_permlane32_swap_b32 %0, %1" : "+v"(c00), "+v"(c10));
    asm("v_permlane32_swap_b32 %0, %1" : "+v"(c01), "+v"(c11));
    asm("v_permlane32_swap_b32 %0, %1" : "+v"(c20), "+v"(c30));
    asm("v_permlane32_swap_b32 %0, %1" : "+v"(c21), "+v"(c31));
    union U { uint4 u; bf16x8 v; };
    U pa0, pa1;
    pa0.u = make_uint4(c00, c01, c10, c11);
    pa1.u = make_uint4(c20, c21, c30, c31);

    // row-sum via ones-MFMA: runs on the (otherwise idle) matrix pipe, off the VALU chain
    sums = __builtin_amdgcn_mfma_f32_32x32x16_bf16(ones, pa0.v, sums, 0, 0, 0);
    sums = __builtin_amdgcn_mfma_f32_32x32x16_bf16(ones, pa1.v, sums, 0, 0, 0);
    o = __builtin_amdgcn_mfma_f32_32x32x16_bf16(vf0, pa0.v, o, 0, 0, 0);
    o = __builtin_amdgcn_mfma_f32_32x32x16_bf16(vf1, pa1.v, o, 0, 0, 0);
}

// one full (non-diagonal) 128-key round with all 8 K loads hoisted to the top
__device__ __forceinline__ void attn_round_full(const unsigned short* __restrict__ kw_bh, int k0,
                                                const char* __restrict__ vhalf,
                                                bf16x8 qf0, bf16x8 qf1, const f32x16& zf, bf16x8 ones,
                                                int lane31, int hh,
                                                f32x16& o, f32x16& sums) {
    const unsigned short* kp = kw_bh + (size_t)(k0 + lane31) * 32 + hh * 8;
    bf16x8 kf[8];
#pragma unroll
    for (int c = 0; c < 4; ++c) {
        kf[2 * c]     = *(const bf16x8*)(kp + c * 1024);
        kf[2 * c + 1] = *(const bf16x8*)(kp + c * 1024 + 16);
    }
#pragma unroll
    for (int c = 0; c < 4; ++c)
        attn_sub(kf[2 * c], kf[2 * c + 1], vhalf, c, qf0, qf1, zf, ones, lane31, hh, false, o, sums);
}

__global__ __launch_bounds__(256, 4) void k_attn(const unsigned short* __restrict__ qw,
                                                 const unsigned short* __restrict__ kw,
                                                 const unsigned short* __restrict__ vw,
                                                 unsigned short* __restrict__ att) {
    __shared__ __align__(16) char smem[2 * SLOT_STRIDE];

    const int tid = threadIdx.x;
    const int w = tid >> 6, l = tid & 63;
    const int lane31 = l & 31, hh = l >> 5;

    // XCD pinning (validated R4). Balanced per-CU mt sets {e, 31-e, 8+e, 23-e}.
    const int B = blockIdx.x;
    const int xcd = B & 7, idx = B >> 3;       // idx in [0,128)
    const int bh = xcd * 4 + (idx & 3);
    const int v4 = idx >> 2;                   // [0,32)
    const int j4 = v4 >> 3, d4 = v4 & 7;
    const int mt = (j4 & 1) ? (31 - 8 * (j4 >> 1) - d4) : (8 * (j4 >> 1) + d4);

    const int q = mt * 128 + w * 32 + lane31;
    const int D = (mt + 2) >> 1;               // number of 256-key double-rounds

    const unsigned short* qw_bh = qw + (size_t)bh * 4096 * 32;
    const unsigned short* kw_bh = kw + (size_t)bh * 4096 * 32;
    const unsigned short* vw_bh = vw + (size_t)bh * 131072;

    const bf16x8 qf0 = *(const bf16x8*)(qw_bh + (size_t)q * 32 + hh * 8);
    const bf16x8 qf1 = *(const bf16x8*)(qw_bh + (size_t)q * 32 + hh * 8 + 16);

    // V staging: blocked source; per double-round each thread moves 64B (2x16B per 128-key half)
    const unsigned short* vsrc = vw_bh + tid * 16;
    const int vd0 = ((tid & 7) * 2) * VC_STRIDE + (tid >> 3) * 16;

    f32x16 o, sums, zf;
#pragma unroll
    for (int r = 0; r < 16; ++r) { o[r] = 0.f; sums[r] = 0.f; zf[r] = 0.f; }

    union OU { unsigned int u[4]; bf16x8 v; };
    OU onesU;
#pragma unroll
    for (int jj = 0; jj < 4; ++jj) onesU.u[jj] = 0x3F803F80u;  // bf16 1.0 x2
    const bf16x8 ones = onesU.v;

    // prologue: stage double-round 0 (128-key rounds 0 and 1) into slot 0
    {
        uint4 a0 = *(const uint4*)(vsrc);
        uint4 a1 = *(const uint4*)(vsrc + 8);
        uint4 b0 = *(const uint4*)(vsrc + 4096);
        uint4 b1 = *(const uint4*)(vsrc + 4096 + 8);
        *(uint4*)(smem + vd0)                           = a0;
        *(uint4*)(smem + vd0 + VC_STRIDE)               = a1;
        *(uint4*)(smem + HALF_STRIDE + vd0)             = b0;
        *(uint4*)(smem + HALF_STRIDE + vd0 + VC_STRIDE) = b1;
    }

    int cur = 0;
    // main double-rounds: both 128-key halves fully below the diagonal for all 4 waves
    for (int d = 0; d < D - 1; ++d) {
        const unsigned short* vp = vsrc + (size_t)(d + 1) * 8192;
        uint4 a0 = *(const uint4*)(vp);
        uint4 a1 = *(const uint4*)(vp + 8);
        uint4 b0 = *(const uint4*)(vp + 4096);
        uint4 b1 = *(const uint4*)(vp + 4096 + 8);

        __syncthreads();
        const char* vbase = smem + cur * SLOT_STRIDE;
        attn_round_full(kw_bh, 256 * d,       vbase,               qf0, qf1, zf, ones, lane31, hh, o, sums);
        attn_round_full(kw_bh, 256 * d + 128, vbase + HALF_STRIDE, qf0, qf1, zf, ones, lane31, hh, o, sums);

        char* nb = smem + (cur ^ 1) * SLOT_STRIDE;
        *(uint4*)(nb + vd0)                           = a0;
        *(uint4*)(nb + vd0 + VC_STRIDE)               = a1;
        *(uint4*)(nb + HALF_STRIDE + vd0)             = b0;
        *(uint4*)(nb + HALF_STRIDE + vd0 + VC_STRIDE) = b1;
        cur ^= 1;
    }

    __syncthreads();
    // last double-round in slot cur: (mt odd) full round mt-1 in half0, diagonal round mt in half1
    //                                (mt even) diagonal round mt in half0
    {
        const char* vbase = smem + cur * SLOT_STRIDE;
        const char* dv = vbase;
        if (mt & 1) {
            attn_round_full(kw_bh, 128 * (mt - 1), vbase, qf0, qf1, zf, ones, lane31, hh, o, sums);
            dv = vbase + HALF_STRIDE;
        }
        // diagonal round (keys 128*mt ..): wave w runs subs 0..w, mask at c==w
        const unsigned short* kp = kw_bh + (size_t)(128 * mt + lane31) * 32 + hh * 8;
        bf16x8 kf[8];
#pragma unroll
        for (int c = 0; c < 4; ++c) {
            kf[2 * c]     = *(const bf16x8*)(kp + c * 1024);
            kf[2 * c + 1] = *(const bf16x8*)(kp + c * 1024 + 16);
        }
#pragma unroll
        for (int c = 0; c < 4; ++c)
            if (c <= w)
                attn_sub(kf[2 * c], kf[2 * c + 1], dv, c, qf0, qf1, zf, ones, lane31, hh, c == w, o, sums);
    }

    const float inv = 1.0f / sums[0];
    unsigned int* dst = (unsigned int*)(att + (((size_t)(bh >> 3)) * 4096 + q) * 256 + (bh & 7) * 32);
#pragma unroll
    for (int jj = 0; jj < 8; ++jj) {
        unsigned int v = pk_bf16(o[2 * jj] * inv, o[2 * jj + 1] * inv);
        dst[(jj & 1) + 4 * (jj >> 1) + 2 * hh] = v;
    }
}

// ---------- output projection ----------
__global__ __launch_bounds__(256) void k_proj(const unsigned short* __restrict__ wpb,
                                              const unsigned short* __restrict__ att,
                                              const float* __restrict__ bp,
                                              float* __restrict__ out) {
    __shared__ unsigned short As[128 * 32];
    __shared__ unsigned short Bs[128 * 32];
    const int b = blockIdx.z;
    const int o0 = blockIdx.y * 128, s0 = blockIdx.x * 128;
    const int tid = threadIdx.x;
    const int w = tid >> 6, l = tid & 63, g = l >> 4, lc = l & 15;
    const int wr = w >> 1, wc = w & 1;
    const unsigned short* ab = att + (size_t)b * 4096 * 256;

    f32x4 acc[4][4];
#pragma unroll
    for (int m = 0; m < 4; ++m)
#pragma unroll
        for (int nf = 0; nf < 4; ++nf) acc[m][nf] = (f32x4)(0.f);

    const int lrow = tid >> 1, lhalf = tid & 1;
    const int lsw0 = (lrow * 64 + lhalf * 32) ^ ((lrow & 7) << 4);
    const int lsw1 = (lrow * 64 + lhalf * 32 + 16) ^ ((lrow & 7) << 4);

    for (int kk = 0; kk < 8; ++kk) {
        const int c0 = kk * 32;
        __syncthreads();
        {
            const uint4* srcA = (const uint4*)(wpb + (size_t)(o0 + lrow) * 256 + c0 + lhalf * 16);
            uint4 a0 = srcA[0], a1 = srcA[1];
            const uint4* srcB = (const uint4*)(ab + (size_t)(s0 + lrow) * 256 + c0 + lhalf * 16);
            uint4 b0 = srcB[0], b1 = srcB[1];
            *(uint4*)((char*)As + lsw0) = a0;
            *(uint4*)((char*)As + lsw1) = a1;
            *(uint4*)((char*)Bs + lsw0) = b0;
            *(uint4*)((char*)Bs + lsw1) = b1;
        }
        __syncthreads();
        bf16x8 af[4], bfv[4];
#pragma unroll
        for (int m = 0; m < 4; ++m) {
            int row = wr * 64 + m * 16 + lc;
            af[m] = *(const bf16x8*)((char*)As + ((row * 64 + g * 16) ^ ((row & 7) << 4)));
        }
#pragma unroll
        for (int nf = 0; nf < 4; ++nf) {
            int row = wc * 64 + nf * 16 + lc;
            bfv[nf] = *(const bf16x8*)((char*)Bs + ((row * 64 + g * 16) ^ ((row & 7) << 4)));
        }
#pragma unroll
        for (int m = 0; m < 4; ++m)
#pragma unroll
            for (int nf = 0; nf < 4; ++nf)
                acc[m][nf] = __builtin_amdgcn_mfma_f32_16x16x32_bf16(af[m], bfv[nf], acc[m][nf], 0, 0, 0);
    }

#pragma unroll
    for (int m = 0; m < 4; ++m)
#pragma unroll
        for (int nf = 0; nf < 4; ++nf)
#pragma unroll
            for (int i = 0; i < 4; ++i) {
                int o = o0 + wr * 64 + m * 16 + g * 4 + i;
                int s = s0 + wc * 64 + nf * 16 + lc;
                out[((size_t)(b * 256 + o)) * 4096 + s] = acc[m][nf][i] + bp[o];
            }
}

extern "C" void kernel_launch(void* const* d_in, const int* in_sizes, int n_in,
                              void* d_out, int out_size, void* d_ws, size_t ws_size,
                              hipStream_t stream) {
    const float* x   = (const float*)d_in[0];
    const float* Wq  = (const float*)d_in[1];
    const float* bq  = (const float*)d_in[2];
    const float* Wkv = (const float*)d_in[3];
    const float* bkv = (const float*)d_in[4];
    const float* Wp  = (const float*)d_in[5];
    const float* bp  = (const float*)d_in[6];
    float* out = (float*)d_out;
    char* ws = (char*)d_ws;

    unsigned short* wb  = (unsigned short*)(ws);              // 768*256*2
    unsigned short* wpb = (unsigned short*)(ws + 393216);     // 256*256*2
    unsigned short* xT  = (unsigned short*)(ws + 524288);     // 8 MB
    unsigned short* qws = (unsigned short*)(ws + 8912896);
    unsigned short* kws = (unsigned short*)(ws + 17301504);
    unsigned short* vws = (unsigned short*)(ws + 25690112);
    unsigned short* att = (unsigned short*)(ws + 34078720);

    hipLaunchKernelGGL(k_xt, dim3(64, 4, 5), dim3(256), 0, stream, x, xT, Wq, Wkv, Wp, wb, wpb);
    hipLaunchKernelGGL(k_qkv, dim3(32, 6, 4), dim3(256), 0, stream, wb, xT, bq, bkv, qws, kws, vws);
    hipLaunchKernelGGL(k_attn, dim3(1024), dim3(256), 0, stream, qws, kws, vws, att);
    hipLaunchKernelGGL(k_proj, dim3(32, 2, 4), dim3(256), 0, stream, wpb, att, bp, out);
}

// Round 19
// 97.000 us; speedup vs baseline: 1.2651x; 1.1576x over previous
//
#include <hip/hip_runtime.h>

typedef __bf16 bf16x8 __attribute__((ext_vector_type(8)));
typedef float f32x4 __attribute__((ext_vector_type(4)));
typedef float f32x16 __attribute__((ext_vector_type(16)));

#define S_LEN 4096

__device__ __forceinline__ unsigned short f2bf(float f) {
    unsigned int u = __float_as_uint(f);
    u += 0x7fffu + ((u >> 16) & 1u);
    return (unsigned short)(u >> 16);
}

__device__ __forceinline__ unsigned int pk_bf16(float lo, float hi) {
    unsigned int r;
    asm("v_cvt_pk_bf16_f32 %0, %1, %2" : "=v"(r) : "v"(lo), "v"(hi));
    return r;
}

// ---------- x (b,c,s) f32 -> xT (b,s,c) bf16 ; z==4 slice does weight conversion ----------
__global__ __launch_bounds__(256) void k_xt(const float* __restrict__ x, unsigned short* __restrict__ xT,
                                            const float* __restrict__ Wq, const float* __restrict__ Wkv,
                                            const float* __restrict__ Wp, unsigned short* __restrict__ wb,
                                            unsigned short* __restrict__ wpb) {
    __shared__ unsigned short tile[64 * 80];
    const int tid = threadIdx.x;
    if (blockIdx.z == 4) {
        const int bi = blockIdx.x + 64 * blockIdx.y;
        for (int i = bi * 256 + tid; i < 262144; i += 65536) {
            if (i < 65536)       wb[i]           = f2bf(Wq[i]);
            else if (i < 196608) wb[i]           = f2bf(Wkv[i - 65536]);
            else                 wpb[i - 196608] = f2bf(Wp[i - 196608]);
        }
        return;
    }
    const int b = blockIdx.z, c0 = blockIdx.y * 64, s0 = blockIdx.x * 64;
#pragma unroll
    for (int ii = 0; ii < 4; ++ii) {
        int flat = ii * 256 + tid;
        int cr = flat >> 4, s4 = flat & 15;
        const float4 v = *(const float4*)(x + ((size_t)(b * 256 + c0 + cr)) * S_LEN + s0 + s4 * 4);
        tile[(s4 * 4 + 0) * 80 + cr] = f2bf(v.x);
        tile[(s4 * 4 + 1) * 80 + cr] = f2bf(v.y);
        tile[(s4 * 4 + 2) * 80 + cr] = f2bf(v.z);
        tile[(s4 * 4 + 3) * 80 + cr] = f2bf(v.w);
    }
    __syncthreads();
#pragma unroll
    for (int ii = 0; ii < 2; ++ii) {
        int flat = ii * 256 + tid;
        int sr = flat >> 3, ch = flat & 7;
        uint4 u = *(const uint4*)&tile[sr * 80 + ch * 8];
        *(uint4*)(xT + ((size_t)(b * 4096 + s0 + sr)) * 256 + c0 + ch * 8) = u;
    }
}

// ---------- QKV GEMM -> q (pre-scaled) / k [b][h][s][32], v blocked [b][h][s/128][d][s%128] ----------
// epilogue: q/k use packed 8B stores (i=0..3 contiguous in d); v stays scalar (half-coalesced in s)
__global__ __launch_bounds__(256) void k_qkv(const unsigned short* __restrict__ wb,
                                             const unsigned short* __restrict__ xT,
                                             const float* __restrict__ bq,
                                             const float* __restrict__ bkv,
                                             unsigned short* __restrict__ qws,
                                             unsigned short* __restrict__ kws,
                                             unsigned short* __restrict__ vws) {
    __shared__ unsigned short As[128 * 32];
    __shared__ unsigned short Bs[128 * 32];
    const int b = blockIdx.z;
    const int o0 = blockIdx.y * 128, s0 = blockIdx.x * 128;
    const int tid = threadIdx.x;
    const int w = tid >> 6, l = tid & 63, g = l >> 4, lc = l & 15;
    const int wr = w >> 1, wc = w & 1;
    const unsigned short* xb = xT + (size_t)b * 4096 * 256;
    const float SM_C = 0.25505654458f;  // log2(e)/sqrt(32) folded into q

    f32x4 acc[4][4];
#pragma unroll
    for (int m = 0; m < 4; ++m)
#pragma unroll
        for (int nf = 0; nf < 4; ++nf) acc[m][nf] = (f32x4)(0.f);

    const int lrow = tid >> 1, lhalf = tid & 1;
    const int lsw0 = (lrow * 64 + lhalf * 32) ^ ((lrow & 7) << 4);
    const int lsw1 = (lrow * 64 + lhalf * 32 + 16) ^ ((lrow & 7) << 4);

    for (int kk = 0; kk < 8; ++kk) {
        const int c0 = kk * 32;
        __syncthreads();
        {
            const uint4* srcA = (const uint4*)(wb + (size_t)(o0 + lrow) * 256 + c0 + lhalf * 16);
            uint4 a0 = srcA[0], a1 = srcA[1];
            const uint4* srcB = (const uint4*)(xb + (size_t)(s0 + lrow) * 256 + c0 + lhalf * 16);
            uint4 b0 = srcB[0], b1 = srcB[1];
            *(uint4*)((char*)As + lsw0) = a0;
            *(uint4*)((char*)As + lsw1) = a1;
            *(uint4*)((char*)Bs + lsw0) = b0;
            *(uint4*)((char*)Bs + lsw1) = b1;
        }
        __syncthreads();
        bf16x8 af[4], bfv[4];
#pragma unroll
        for (int m = 0; m < 4; ++m) {
            int row = wr * 64 + m * 16 + lc;
            af[m] = *(const bf16x8*)((char*)As + ((row * 64 + g * 16) ^ ((row & 7) << 4)));
        }
#pragma unroll
        for (int nf = 0; nf < 4; ++nf) {
            int row = wc * 64 + nf * 16 + lc;
            bfv[nf] = *(const bf16x8*)((char*)Bs + ((row * 64 + g * 16) ^ ((row & 7) << 4)));
        }
#pragma unroll
        for (int m = 0; m < 4; ++m)
#pragma unroll
            for (int nf = 0; nf < 4; ++nf)
                acc[m][nf] = __builtin_amdgcn_mfma_f32_16x16x32_bf16(af[m], bfv[nf], acc[m][nf], 0, 0, 0);
    }

#pragma unroll
    for (int m = 0; m < 4; ++m)
#pragma unroll
        for (int nf = 0; nf < 4; ++nf) {
            const int ob = o0 + wr * 64 + m * 16 + g * 4;   // base o for i=0..3 (contiguous in d)
            const int s = s0 + wc * 64 + nf * 16 + lc;
            if (ob < 256) {
                const int h = ob >> 5, d = ob & 31;
                float v0 = (acc[m][nf][0] + bq[ob + 0]) * SM_C;
                float v1 = (acc[m][nf][1] + bq[ob + 1]) * SM_C;
                float v2 = (acc[m][nf][2] + bq[ob + 2]) * SM_C;
                float v3 = (acc[m][nf][3] + bq[ob + 3]) * SM_C;
                uint2 pk = make_uint2(pk_bf16(v0, v1), pk_bf16(v2, v3));
                *(uint2*)(qws + (((size_t)(b * 8 + h)) * 4096 + s) * 32 + d) = pk;
            } else if (ob < 512) {
                const int oo = ob - 256, h = oo >> 5, d = oo & 31;
                float v0 = acc[m][nf][0] + bkv[oo + 0];
                float v1 = acc[m][nf][1] + bkv[oo + 1];
                float v2 = acc[m][nf][2] + bkv[oo + 2];
                float v3 = acc[m][nf][3] + bkv[oo + 3];
                uint2 pk = make_uint2(pk_bf16(v0, v1), pk_bf16(v2, v3));
                *(uint2*)(kws + (((size_t)(b * 8 + h)) * 4096 + s) * 32 + d) = pk;
            } else {
#pragma unroll
                for (int i = 0; i < 4; ++i) {
                    const int oo = ob + i - 512, h = oo >> 5, d = oo & 31;
                    vws[(size_t)(b * 8 + h) * 131072 + (((s >> 7) * 32 + d) << 7) + (s & 127)] =
                        f2bf(acc[m][nf][i] + bkv[oo]);
                }
            }
        }
}

// ---------- causal flash attention: 128-q block (4 waves), K hoisted per 128-key round,
// ---------- V blocked-global -> LDS, 256-key double rounds (1 barrier pair / 8 subs) ----------
#define VC_STRIDE 544
#define HALF_STRIDE 8704     // 16 * 544  (one 128-key round)
#define SLOT_STRIDE 17408    // two 128-key rounds per slot

__device__ __forceinline__ void attn_sub(bf16x8 kf0, bf16x8 kf1,
                                         const char* __restrict__ vbuf, int c,
                                         bf16x8 qf0, bf16x8 qf1, const f32x16& zf, bf16x8 ones,
                                         int lane31, int hh, bool domask,
                                         f32x16& o, f32x16& sums) {
    bf16x8 vf0 = *(const bf16x8*)(vbuf + (c * 4 + hh) * VC_STRIDE + lane31 * 16);
    bf16x8 vf1 = *(const bf16x8*)(vbuf + (c * 4 + 2 + hh) * VC_STRIDE + lane31 * 16);

    f32x16 s = __builtin_amdgcn_mfma_f32_32x32x16_bf16(kf0, qf0, zf, 0, 0, 0);
    s = __builtin_amdgcn_mfma_f32_32x32x16_bf16(kf1, qf1, s, 0, 0, 0);

    if (domask) {
#pragma unroll
        for (int r = 0; r < 16; ++r) {
            int krel = (r & 3) + 8 * (r >> 2) + 4 * hh;
            if (krel > lane31) s[r] = -1e30f;
        }
    }

    float p[16];
#pragma unroll
    for (int r = 0; r < 16; ++r) p[r] = __builtin_amdgcn_exp2f(s[r]);

    unsigned int c00 = pk_bf16(p[0], p[1]),   c01 = pk_bf16(p[2], p[3]);
    unsigned int c10 = pk_bf16(p[4], p[5]),   c11 = pk_bf16(p[6], p[7]);
    unsigned int c20 = pk_bf16(p[8], p[9]),   c21 = pk_bf16(p[10], p[11]);
    unsigned int c30 = pk_bf16(p[12], p[13]), c31 = pk_bf16(p[14], p[15]);
    asm("v_permlane32_swap_b32 %0, %1" : "+v"(c00), "+v"(c10));
    asm("v_permlane32_swap_b32 %0, %1" : "+v"(c01), "+v"(c11));
    asm("v_permlane32_swap_b32 %0, %1" : "+v"(c20), "+v"(c30));
    asm("v_permlane32_swap_b32 %0, %1" : "+v"(c21), "+v"(c31));
    union U { uint4 u; bf16x8 v; };
    U pa0, pa1;
    pa0.u = make_uint4(c00, c01, c10, c11);
    pa1.u = make_uint4(c20, c21, c30, c31);

    // row-sum via ones-MFMA: runs on the (otherwise idle) matrix pipe, off the VALU chain
    sums = __builtin_amdgcn_mfma_f32_32x32x16_bf16(ones, pa0.v, sums, 0, 0, 0);
    sums = __builtin_amdgcn_mfma_f32_32x32x16_bf16(ones, pa1.v, sums, 0, 0, 0);
    o = __builtin_amdgcn_mfma_f32_32x32x16_bf16(vf0, pa0.v, o, 0, 0, 0);
    o = __builtin_amdgcn_mfma_f32_32x32x16_bf16(vf1, pa1.v, o, 0, 0, 0);
}

// one full (non-diagonal) 128-key round with all 8 K loads hoisted to the top
__device__ __forceinline__ void attn_round_full(const unsigned short* __restrict__ kw_bh, int k0,
                                                const char* __restrict__ vhalf,
                                                bf16x8 qf0, bf16x8 qf1, const f32x16& zf, bf16x8 ones,
                                                int lane31, int hh,
                                                f32x16& o, f32x16& sums) {
    const unsigned short* kp = kw_bh + (size_t)(k0 + lane31) * 32 + hh * 8;
    bf16x8 kf[8];
#pragma unroll
    for (int c = 0; c < 4; ++c) {
        kf[2 * c]     = *(const bf16x8*)(kp + c * 1024);
        kf[2 * c + 1] = *(const bf16x8*)(kp + c * 1024 + 16);
    }
#pragma unroll
    for (int c = 0; c < 4; ++c)
        attn_sub(kf[2 * c], kf[2 * c + 1], vhalf, c, qf0, qf1, zf, ones, lane31, hh, false, o, sums);
}

__global__ __launch_bounds__(256, 4) void k_attn(const unsigned short* __restrict__ qw,
                                                 const unsigned short* __restrict__ kw,
                                                 const unsigned short* __restrict__ vw,
                                                 unsigned short* __restrict__ att) {
    __shared__ __align__(16) char smem[2 * SLOT_STRIDE];

    const int tid = threadIdx.x;
    const int w = tid >> 6, l = tid & 63;
    const int lane31 = l & 31, hh = l >> 5;

    // XCD pinning (validated R4). Balanced per-CU mt sets {e, 31-e, 8+e, 23-e}.
    const int B = blockIdx.x;
    const int xcd = B & 7, idx = B >> 3;       // idx in [0,128)
    const int bh = xcd * 4 + (idx & 3);
    const int v4 = idx >> 2;                   // [0,32)
    const int j4 = v4 >> 3, d4 = v4 & 7;
    const int mt = (j4 & 1) ? (31 - 8 * (j4 >> 1) - d4) : (8 * (j4 >> 1) + d4);

    const int q = mt * 128 + w * 32 + lane31;
    const int D = (mt + 2) >> 1;               // number of 256-key double-rounds

    const unsigned short* qw_bh = qw + (size_t)bh * 4096 * 32;
    const unsigned short* kw_bh = kw + (size_t)bh * 4096 * 32;
    const unsigned short* vw_bh = vw + (size_t)bh * 131072;

    const bf16x8 qf0 = *(const bf16x8*)(qw_bh + (size_t)q * 32 + hh * 8);
    const bf16x8 qf1 = *(const bf16x8*)(qw_bh + (size_t)q * 32 + hh * 8 + 16);

    // V staging: blocked source; per double-round each thread moves 64B (2x16B per 128-key half)
    const unsigned short* vsrc = vw_bh + tid * 16;
    const int vd0 = ((tid & 7) * 2) * VC_STRIDE + (tid >> 3) * 16;

    f32x16 o, sums, zf;
#pragma unroll
    for (int r = 0; r < 16; ++r) { o[r] = 0.f; sums[r] = 0.f; zf[r] = 0.f; }

    union OU { unsigned int u[4]; bf16x8 v; };
    OU onesU;
#pragma unroll
    for (int jj = 0; jj < 4; ++jj) onesU.u[jj] = 0x3F803F80u;  // bf16 1.0 x2
    const bf16x8 ones = onesU.v;

    // prologue: stage double-round 0 (128-key rounds 0 and 1) into slot 0
    {
        uint4 a0 = *(const uint4*)(vsrc);
        uint4 a1 = *(const uint4*)(vsrc + 8);
        uint4 b0 = *(const uint4*)(vsrc + 4096);
        uint4 b1 = *(const uint4*)(vsrc + 4096 + 8);
        *(uint4*)(smem + vd0)                           = a0;
        *(uint4*)(smem + vd0 + VC_STRIDE)               = a1;
        *(uint4*)(smem + HALF_STRIDE + vd0)             = b0;
        *(uint4*)(smem + HALF_STRIDE + vd0 + VC_STRIDE) = b1;
    }

    int cur = 0;
    // main double-rounds: both 128-key halves fully below the diagonal for all 4 waves
    for (int d = 0; d < D - 1; ++d) {
        const unsigned short* vp = vsrc + (size_t)(d + 1) * 8192;
        uint4 a0 = *(const uint4*)(vp);
        uint4 a1 = *(const uint4*)(vp + 8);
        uint4 b0 = *(const uint4*)(vp + 4096);
        uint4 b1 = *(const uint4*)(vp + 4096 + 8);

        __syncthreads();
        const char* vbase = smem + cur * SLOT_STRIDE;
        attn_round_full(kw_bh, 256 * d,       vbase,               qf0, qf1, zf, ones, lane31, hh, o, sums);
        attn_round_full(kw_bh, 256 * d + 128, vbase + HALF_STRIDE, qf0, qf1, zf, ones, lane31, hh, o, sums);

        char* nb = smem + (cur ^ 1) * SLOT_STRIDE;
        *(uint4*)(nb + vd0)                           = a0;
        *(uint4*)(nb + vd0 + VC_STRIDE)               = a1;
        *(uint4*)(nb + HALF_STRIDE + vd0)             = b0;
        *(uint4*)(nb + HALF_STRIDE + vd0 + VC_STRIDE) = b1;
        cur ^= 1;
    }

    __syncthreads();
    // last double-round in slot cur: (mt odd) full round mt-1 in half0, diagonal round mt in half1
    //                                (mt even) diagonal round mt in half0
    {
        const char* vbase = smem + cur * SLOT_STRIDE;
        const char* dv = vbase;
        if (mt & 1) {
            attn_round_full(kw_bh, 128 * (mt - 1), vbase, qf0, qf1, zf, ones, lane31, hh, o, sums);
            dv = vbase + HALF_STRIDE;
        }
        // diagonal round (keys 128*mt ..): wave w runs subs 0..w, mask at c==w
        const unsigned short* kp = kw_bh + (size_t)(128 * mt + lane31) * 32 + hh * 8;
        bf16x8 kf[8];
#pragma unroll
        for (int c = 0; c < 4; ++c) {
            kf[2 * c]     = *(const bf16x8*)(kp + c * 1024);
            kf[2 * c + 1] = *(const bf16x8*)(kp + c * 1024 + 16);
        }
#pragma unroll
        for (int c = 0; c < 4; ++c)
            if (c <= w)
                attn_sub(kf[2 * c], kf[2 * c + 1], dv, c, qf0, qf1, zf, ones, lane31, hh, c == w, o, sums);
    }

    const float inv = 1.0f / sums[0];
    unsigned int* dst = (unsigned int*)(att + (((size_t)(bh >> 3)) * 4096 + q) * 256 + (bh & 7) * 32);
#pragma unroll
    for (int jj = 0; jj < 8; ++jj) {
        unsigned int v = pk_bf16(o[2 * jj] * inv, o[2 * jj + 1] * inv);
        dst[(jj & 1) + 4 * (jj >> 1) + 2 * hh] = v;
    }
}

// ---------- output projection ----------
__global__ __launch_bounds__(256) void k_proj(const unsigned short* __restrict__ wpb,
                                              const unsigned short* __restrict__ att,
                                              const float* __restrict__ bp,
                                              float* __restrict__ out) {
    __shared__ unsigned short As[128 * 32];
    __shared__ unsigned short Bs[128 * 32];
    const int b = blockIdx.z;
    const int o0 = blockIdx.y * 128, s0 = blockIdx.x * 128;
    const int tid = threadIdx.x;
    const int w = tid >> 6, l = tid & 63, g = l >> 4, lc = l & 15;
    const int wr = w >> 1, wc = w & 1;
    const unsigned short* ab = att + (size_t)b * 4096 * 256;

    f32x4 acc[4][4];
#pragma unroll
    for (int m = 0; m < 4; ++m)
#pragma unroll
        for (int nf = 0; nf < 4; ++nf) acc[m][nf] = (f32x4)(0.f);

    const int lrow = tid >> 1, lhalf = tid & 1;
    const int lsw0 = (lrow * 64 + lhalf * 32) ^ ((lrow & 7) << 4);
    const int lsw1 = (lrow * 64 + lhalf * 32 + 16) ^ ((lrow & 7) << 4);

    for (int kk = 0; kk < 8; ++kk) {
        const int c0 = kk * 32;
        __syncthreads();
        {
            const uint4* srcA = (const uint4*)(wpb + (size_t)(o0 + lrow) * 256 + c0 + lhalf * 16);
            uint4 a0 = srcA[0], a1 = srcA[1];
            const uint4* srcB = (const uint4*)(ab + (size_t)(s0 + lrow) * 256 + c0 + lhalf * 16);
            uint4 b0 = srcB[0], b1 = srcB[1];
            *(uint4*)((char*)As + lsw0) = a0;
            *(uint4*)((char*)As + lsw1) = a1;
            *(uint4*)((char*)Bs + lsw0) = b0;
            *(uint4*)((char*)Bs + lsw1) = b1;
        }
        __syncthreads();
        bf16x8 af[4], bfv[4];
#pragma unroll
        for (int m = 0; m < 4; ++m) {
            int row = wr * 64 + m * 16 + lc;
            af[m] = *(const bf16x8*)((char*)As + ((row * 64 + g * 16) ^ ((row & 7) << 4)));
        }
#pragma unroll
        for (int nf = 0; nf < 4; ++nf) {
            int row = wc * 64 + nf * 16 + lc;
            bfv[nf] = *(const bf16x8*)((char*)Bs + ((row * 64 + g * 16) ^ ((row & 7) << 4)));
        }
#pragma unroll
        for (int m = 0; m < 4; ++m)
#pragma unroll
            for (int nf = 0; nf < 4; ++nf)
                acc[m][nf] = __builtin_amdgcn_mfma_f32_16x16x32_bf16(af[m], bfv[nf], acc[m][nf], 0, 0, 0);
    }

#pragma unroll
    for (int m = 0; m < 4; ++m)
#pragma unroll
        for (int nf = 0; nf < 4; ++nf)
#pragma unroll
            for (int i = 0; i < 4; ++i) {
                int o = o0 + wr * 64 + m * 16 + g * 4 + i;
                int s = s0 + wc * 64 + nf * 16 + lc;
                out[((size_t)(b * 256 + o)) * 4096 + s] = acc[m][nf][i] + bp[o];
            }
}

extern "C" void kernel_launch(void* const* d_in, const int* in_sizes, int n_in,
                              void* d_out, int out_size, void* d_ws, size_t ws_size,
                              hipStream_t stream) {
    const float* x   = (const float*)d_in[0];
    const float* Wq  = (const float*)d_in[1];
    const float* bq  = (const float*)d_in[2];
    const float* Wkv = (const float*)d_in[3];
    const float* bkv = (const float*)d_in[4];
    const float* Wp  = (const float*)d_in[5];
    const float* bp  = (const float*)d_in[6];
    float* out = (float*)d_out;
    char* ws = (char*)d_ws;

    unsigned short* wb  = (unsigned short*)(ws);              // 768*256*2
    unsigned short* wpb = (unsigned short*)(ws + 393216);     // 256*256*2
    unsigned short* xT  = (unsigned short*)(ws + 524288);     // 8 MB
    unsigned short* qws = (unsigned short*)(ws + 8912896);
    unsigned short* kws = (unsigned short*)(ws + 17301504);
    unsigned short* vws = (unsigned short*)(ws + 25690112);
    unsigned short* att = (unsigned short*)(ws + 34078720);

    hipLaunchKernelGGL(k_xt, dim3(64, 4, 5), dim3(256), 0, stream, x, xT, Wq, Wkv, Wp, wb, wpb);
    hipLaunchKernelGGL(k_qkv, dim3(32, 6, 4), dim3(256), 0, stream, wb, xT, bq, bkv, qws, kws, vws);
    hipLaunchKernelGGL(k_attn, dim3(1024), dim3(256), 0, stream, qws, kws, vws, att);
    hipLaunchKernelGGL(k_proj, dim3(32, 2, 4), dim3(256), 0, stream, wpb, att, bp, out);
}